// Round 22
// baseline (98.729 us; speedup 1.0000x reference)
//
#include <hip/hip_runtime.h>
#include <hip/hip_bf16.h>

typedef __hip_bfloat16 bf16;
typedef short bf16x4 __attribute__((ext_vector_type(4)));
typedef short bf16x8 __attribute__((ext_vector_type(8)));
typedef float f32x4 __attribute__((ext_vector_type(4)));

#define N_B 8
#define N_C 256
#define N_H 4
#define N_N 2304
#define N_ELEM 589824   // N_C * N_N

static __device__ __forceinline__ f32x4 mfma32(bf16x8 a, bf16x8 b, f32x4 c) {
  return __builtin_amdgcn_mfma_f32_16x16x32_bf16(a, b, c, 0, 0, 0);
}
static __device__ __forceinline__ short bfs(float f) {
  union { __hip_bfloat16 h; short s; } u;
  u.h = __float2bfloat16(f);
  return u.s;
}
static __device__ __forceinline__ float fexp2(float x) {
#if __has_builtin(__builtin_amdgcn_exp2f)
  return __builtin_amdgcn_exp2f(x);   // raw v_exp_f32; inputs bounded here
#else
  return exp2f(x);
#endif
}
struct TrueT  { static constexpr bool value = true;  };
struct FalseT { static constexpr bool value = false; };

// fragment-order index for weight matrices: element (row, c) ->
// ((ot*4+mb)*8+kk)*512 + (g*16+l15)*8 + e   (lane-contiguous A loads)
static __device__ __forceinline__ size_t wfrag_idx(int row, int c) {
  int ot = row >> 6, rlo = row & 63;
  int mb = rlo >> 4, l15 = rlo & 15;
  int kk = c >> 5, clo = c & 31;
  int gg = clo >> 3, e = clo & 7;
  return ((size_t)((ot * 4 + mb) * 8 + kk)) * 512 + (size_t)(gg * 16 + l15) * 8 + e;
}

// ---------------- fused prelude: gn_stats | mask_scan | w_conv --------------
__global__ __launch_bounds__(256) void prelude(const float* __restrict__ x,
                                               const int* __restrict__ mask,
                                               const float* __restrict__ wq,
                                               const float* __restrict__ wp,
                                               float* __restrict__ part,
                                               int* __restrict__ cidx,
                                               int* __restrict__ count,
                                               bf16* __restrict__ wqb,
                                               bf16* __restrict__ wpb) {
  __shared__ int sbuf[256];
  int bid = blockIdx.x, tid = threadIdx.x;
  if (bid < 256) {
    int b = bid >> 5, chunk = bid & 31;
    const f32x4* p = (const f32x4*)(x + (size_t)b * N_ELEM + (size_t)chunk * 18432);
    float s = 0.f, ss = 0.f;
    for (int i = tid; i < 4608; i += 256) {
      f32x4 v = p[i];
      s  += (v[0] + v[1]) + (v[2] + v[3]);
      ss += (v[0] * v[0] + v[1] * v[1]) + (v[2] * v[2] + v[3] * v[3]);
    }
    for (int off = 32; off; off >>= 1) {
      s  += __shfl_xor(s, off);
      ss += __shfl_xor(ss, off);
    }
    float* ls = (float*)sbuf;
    int wv = tid >> 6;
    if ((tid & 63) == 0) { ls[wv] = s; ls[4 + wv] = ss; }
    __syncthreads();
    if (tid == 0) {
      part[bid * 2]     = ls[0] + ls[1] + ls[2] + ls[3];
      part[bid * 2 + 1] = ls[4] + ls[5] + ls[6] + ls[7];
    }
  } else if (bid < 264) {
    int b = bid - 256;
    const int* mb = mask + b * N_N;
    int flags[9], tot = 0;
    for (int r = 0; r < 9; ++r) {
      int f = (mb[tid * 9 + r] != 0) ? 1 : 0;
      flags[r] = f; tot += f;
    }
    sbuf[tid] = tot;
    __syncthreads();
    for (int off = 1; off < 256; off <<= 1) {
      int v = (tid >= off) ? sbuf[tid - off] : 0;
      __syncthreads();
      sbuf[tid] += v;
      __syncthreads();
    }
    int pos = sbuf[tid] - tot;
    int total = sbuf[255];
    int* cb = cidx + b * N_N;
    for (int r = 0; r < 9; ++r)
      if (flags[r]) cb[pos++] = tid * 9 + r;
    for (int j = total + tid; j < N_N; j += 256) cb[j] = 0;  // finite pad
    if (tid == 0) count[b] = total;
  } else {
    int i = (bid - 264) * 256 + tid;
    int row = i >> 8, c = i & 255;
    float sc = (row < 256) ? 0.18033688011112042f : 1.0f;  // 2^-3 * log2(e)
    wqb[wfrag_idx(row, c)] = __float2bfloat16(wq[i] * sc);
    if (i < 65536) wpb[wfrag_idx(row, c)] = __float2bfloat16(wp[i]);
  }
}

// ---------------- fused stats-final + GN + transpose -------------------------
__global__ __launch_bounds__(256) void xt_gn(const float* __restrict__ x,
                                             const float* __restrict__ part,
                                             const float* __restrict__ gnw,
                                             const float* __restrict__ gnb,
                                             bf16* __restrict__ xt) {
  int id = blockIdx.x;               // 1152 = 36nt * 4ct * 8b
  int nt = id % 36, ct = (id / 36) & 3, b = id / 144;
  float s = 0.f, ss = 0.f;
  for (int i = 0; i < 32; ++i) {
    s  += part[b * 64 + i * 2];
    ss += part[b * 64 + i * 2 + 1];
  }
  float mean = s * (1.f / (float)N_ELEM);
  float var  = ss * (1.f / (float)N_ELEM) - mean * mean;
  float rstd = rsqrtf(var + 1e-5f);
  __shared__ bf16 tile[64][65];
  int tn = threadIdx.x & 63, tq = threadIdx.x >> 6;
  const float* xp = x + (size_t)b * N_ELEM + (size_t)(ct * 64) * N_N + nt * 64;
  for (int it = 0; it < 16; ++it) {
    int c = tq * 16 + it;
    int cg = ct * 64 + c;
    float a  = rstd * gnw[cg];
    float dd = gnb[cg] - mean * a;
    tile[c][tn] = __float2bfloat16(xp[(size_t)c * N_N + tn] * a + dd);
  }
  __syncthreads();
  bf16* xo = xt + ((size_t)b * N_N + nt * 64) * 256 + ct * 64;
  for (int it = 0; it < 16; ++it) {
    int nl = tq * 16 + it;
    xo[(size_t)nl * 256 + tn] = tile[tn][nl];
  }
}

// ---------------- QKV GEMM (MFMA; fragment-order A; fragment-order K/V out) -
__global__ __launch_bounds__(256) void qkv_mfma(const bf16* __restrict__ wqb,
                                                const bf16* __restrict__ xt,
                                                const int* __restrict__ cidx,
                                                const int* __restrict__ count,
                                                bf16* __restrict__ qkv) {
  int id = (blockIdx.x & 7) * 216 + (blockIdx.x >> 3);
  int nt = id % 18, ot = (id / 18) % 12, b = id / 216;
  int o0 = ot * 64, n0 = nt * 128;
  int seg = o0 >> 8, h = (o0 >> 6) & 3;
  if (seg != 0) {                     // skip K/V cols beyond ceil128(cnt)
    int cnt128 = (count[b] + 127) & ~127;
    if (n0 >= cnt128) return;
  }
  int lane = threadIdx.x & 63, wave = threadIdx.x >> 6;
  int l15 = lane & 15, g = lane >> 4, g8 = g * 8;
  int jb = n0 + wave * 32;
  int j0 = jb + l15, j1 = j0 + 16;
  int r0 = j0, r1 = j1;
  if (seg != 0) {
    const int* cb = cidx + b * N_N;
    r0 = cb[j0]; r1 = cb[j1];
  }
  const bf16* Af = wqb + (size_t)ot * 16384 + lane * 8;  // fragment-order A
  const bf16* B0 = xt + ((size_t)b * N_N + r0) * 256 + g8;
  const bf16* B1 = xt + ((size_t)b * N_N + r1) * 256 + g8;
  f32x4 z = {0.f, 0.f, 0.f, 0.f};
  f32x4 acc[4][2];
#pragma unroll
  for (int i = 0; i < 4; ++i) { acc[i][0] = z; acc[i][1] = z; }
#pragma unroll
  for (int kk = 0; kk < 8; ++kk) {
    int co = kk * 32;
    bf16x8 b0 = *(const bf16x8*)(B0 + co);
    bf16x8 b1 = *(const bf16x8*)(B1 + co);
#pragma unroll
    for (int mb = 0; mb < 4; ++mb) {
      bf16x8 aa = *(const bf16x8*)(Af + (size_t)(mb * 8 + kk) * 512);
      acc[mb][0] = mfma32(aa, b0, acc[mb][0]);
      acc[mb][1] = mfma32(aa, b1, acc[mb][1]);
    }
  }
  bf16* Base = qkv + ((size_t)seg * (N_B * N_H) + (size_t)b * N_H + h) *
               ((size_t)N_N * 64);
  if (seg == 0) {
#pragma unroll
    for (int mb = 0; mb < 4; ++mb) {
#pragma unroll
      for (int nb = 0; nb < 2; ++nb) {
        int row = jb + nb * 16 + l15;
        int d0 = mb * 16 + g * 4;
        bf16x4 pk = {bfs(acc[mb][nb][0]), bfs(acc[mb][nb][1]),
                     bfs(acc[mb][nb][2]), bfs(acc[mb][nb][3])};
        *reinterpret_cast<bf16x4*>(Base + (size_t)row * 64 + d0) = pk;
      }
    }
  } else if (seg == 1) {
    // Kf fragment blocks (verified R20)
    int kgb = jb >> 4;
#pragma unroll
    for (int mb = 0; mb < 4; ++mb) {
      int hf = mb >> 1;
      int gp = (mb & 1) * 2 + (g >> 1);
      size_t cellbase = (size_t)(gp * 16 + l15) * 8 + (g & 1) * 4;
#pragma unroll
      for (int nb = 0; nb < 2; ++nb) {
        bf16x4 pk = {bfs(acc[mb][nb][0]), bfs(acc[mb][nb][1]),
                     bfs(acc[mb][nb][2]), bfs(acc[mb][nb][3])};
        size_t off = ((size_t)(kgb + nb) * 2 + hf) * 512 + cellbase;
        *reinterpret_cast<bf16x4*>(Base + off) = pk;
      }
    }
  } else {
    // Vf fragment blocks (verified R20)
#pragma unroll
    for (int mb = 0; mb < 4; ++mb) {
#pragma unroll
      for (int nb = 0; nb < 2; ++nb) {
        int n = jb + nb * 16 + l15;
        int kt = n >> 7, nk = n & 127;
        int half = (nk >> 6) & 1, w = (nk >> 4) & 3;
        int gc = (nk >> 2) & 3, ks = nk & 3;
        size_t blk = ((size_t)(kt * 4 + w) * 4 + mb) * 512;
#pragma unroll
        for (int r = 0; r < 4; ++r) {
          int dlo = g * 4 + r;
          Base[blk + (size_t)(gc * 16 + dlo) * 8 + half * 4 + ks] =
              __float2bfloat16(acc[mb][nb][r]);
        }
      }
    }
  }
}

// ---------------- fixed-reference-softmax flash attention -------------------
// R21 structure + next-tile K register prefetch ONLY (+16 regs, ~104 arch
// <= 128 cap; R13's spill was K-prefetch AND V-hoist together, +48 regs).
struct KR { bf16x8 lo0, hi0, lo1, hi1; };

__global__ __launch_bounds__(256, 2) void attn_reg(const bf16* __restrict__ qkv,
                                                   const int* __restrict__ count,
                                                   bf16* __restrict__ ao) {
  int id = (blockIdx.x & 7) * 144 + (blockIdx.x >> 3);
  int qt = id % 36, h = (id / 36) & 3, b = id / 144;
  int tid = threadIdx.x;
  int lane = tid & 63, wave = tid >> 6;
  int l15 = lane & 15, g = lane >> 4, g8 = g * 8;
  int q0 = qt * 64;
  const size_t HSZ = (size_t)N_N * 64;
  const bf16* Qb = qkv + ((size_t)b * N_H + h) * HSZ;
  const bf16* Kf = qkv + ((size_t)(N_B * N_H) + (size_t)b * N_H + h) * HSZ;
  const bf16* Vf = qkv + ((size_t)(2 * N_B * N_H) + (size_t)b * N_H + h) * HSZ;
  int cnt = count[b];

  __shared__ float ssh[4][64];
  __shared__ float obuf[64][65];

  bf16x8 qf[4][2];
#pragma unroll
  for (int qsub = 0; qsub < 4; ++qsub) {
    const bf16* Qp = Qb + (size_t)(q0 + qsub * 16 + l15) * 64;
    qf[qsub][0] = *(const bf16x8*)(Qp + g8);
    qf[qsub][1] = *(const bf16x8*)(Qp + 32 + g8);
  }
  f32x4 z = {0.f, 0.f, 0.f, 0.f};
  f32x4 acc[4][4];   // [dblock][qsub]: O[d=dblock*16+g*4+r][q=qsub*16+l15]
#pragma unroll
  for (int i = 0; i < 4; ++i)
#pragma unroll
    for (int j = 0; j < 4; ++j) acc[i][j] = z;
  float s_r[4] = {0.f, 0.f, 0.f, 0.f};   // lane-local partial denominators
  int kw = wave * 16;
  int lane8 = lane * 8;
  const float NEG = -3.0e38f;

  auto load_k = [&](int kb) {
    KR t;
    int kg0 = (kb >> 4) + wave;
    int kg1 = kg0 + 4;
    t.lo0 = *(const bf16x8*)(Kf + (size_t)(kg0 * 2 + 0) * 512 + lane8);
    t.hi0 = *(const bf16x8*)(Kf + (size_t)(kg0 * 2 + 1) * 512 + lane8);
    t.lo1 = *(const bf16x8*)(Kf + (size_t)(kg1 * 2 + 0) * 512 + lane8);
    t.hi1 = *(const bf16x8*)(Kf + (size_t)(kg1 * 2 + 1) * 512 + lane8);
    return t;
  };

  auto step = [&](const KR& T, int kb, auto tail_t) {
    constexpr bool TAIL = decltype(tail_t)::value;
    int base0 = kb + kw + g * 4, base1 = base0 + 64;
    bf16x8 pb[4];
#pragma unroll
    for (int qsub = 0; qsub < 4; ++qsub) {
      f32x4 s0 = z, s1 = z;
      s0 = mfma32(T.lo0, qf[qsub][0], s0);
      s0 = mfma32(T.hi0, qf[qsub][1], s0);
      s1 = mfma32(T.lo1, qf[qsub][0], s1);
      s1 = mfma32(T.hi1, qf[qsub][1], s1);
      float a0, a1, a2, a3, a4, a5, a6, a7;
      if constexpr (TAIL) {
        a0 = (base0 + 0 < cnt) ? s0[0] : NEG;
        a1 = (base0 + 1 < cnt) ? s0[1] : NEG;
        a2 = (base0 + 2 < cnt) ? s0[2] : NEG;
        a3 = (base0 + 3 < cnt) ? s0[3] : NEG;
        a4 = (base1 + 0 < cnt) ? s1[0] : NEG;
        a5 = (base1 + 1 < cnt) ? s1[1] : NEG;
        a6 = (base1 + 2 < cnt) ? s1[2] : NEG;
        a7 = (base1 + 3 < cnt) ? s1[3] : NEG;
      } else {
        a0 = s0[0]; a1 = s0[1]; a2 = s0[2]; a3 = s0[3];
        a4 = s1[0]; a5 = s1[1]; a6 = s1[2]; a7 = s1[3];
      }
      float p0 = fexp2(a0), p1 = fexp2(a1);
      float p2 = fexp2(a2), p3 = fexp2(a3);
      float p4 = fexp2(a4), p5 = fexp2(a5);
      float p6 = fexp2(a6), p7 = fexp2(a7);
      s_r[qsub] += ((p0 + p1) + (p2 + p3)) + ((p4 + p5) + (p6 + p7));
      pb[qsub] = bf16x8{bfs(p0), bfs(p1), bfs(p2), bfs(p3),
                        bfs(p4), bfs(p5), bfs(p6), bfs(p7)};
    }
    int kt = kb >> 7;
    size_t vbase = (size_t)(kt * 4 + wave) * 4 * 512 + lane8;
#pragma unroll
    for (int dblock = 0; dblock < 4; ++dblock) {
      bf16x8 vf = *(const bf16x8*)(Vf + vbase + (size_t)dblock * 512);
#pragma unroll
      for (int qsub = 0; qsub < 4; ++qsub)
        acc[dblock][qsub] = mfma32(vf, pb[qsub], acc[dblock][qsub]);
    }
  };

  int ntiles = (cnt + 127) >> 7;
  KR cur = load_k(0);
  for (int t = 0; t < ntiles; ++t) {
    KR nxt;
    if (t + 1 < ntiles) nxt = load_k((t + 1) << 7);   // prefetch next K tile
    int kb = t << 7;
    if (kb + 128 <= cnt) step(cur, kb, FalseT{});
    else                 step(cur, kb, TrueT{});
    cur = nxt;
  }

  // ---- denominator: cross-lane (once), then cross-wave via LDS ----
#pragma unroll
  for (int qsub = 0; qsub < 4; ++qsub) {
    float s = s_r[qsub];
    s += __shfl_xor(s, 16);
    s += __shfl_xor(s, 32);
    s_r[qsub] = s;
  }
  if (g == 0) {
#pragma unroll
    for (int qsub = 0; qsub < 4; ++qsub)
      ssh[wave][qsub * 16 + l15] = s_r[qsub];
  }
  __syncthreads();
  float inv[4];
#pragma unroll
  for (int qsub = 0; qsub < 4; ++qsub) {
    int q = qsub * 16 + l15;
    float St = (ssh[0][q] + ssh[1][q]) + (ssh[2][q] + ssh[3][q]);
    inv[qsub] = (St > 0.f) ? (1.f / St) : 0.f;
  }
  // ---- cross-wave O accumulation (pure sums, no rescale) ----
#pragma unroll
  for (int w = 0; w < 4; ++w) {
    if (wave == w) {
#pragma unroll
      for (int dblock = 0; dblock < 4; ++dblock)
#pragma unroll
        for (int qsub = 0; qsub < 4; ++qsub)
#pragma unroll
          for (int r = 0; r < 4; ++r) {
            float v = acc[dblock][qsub][r];
            int row = dblock * 16 + g * 4 + r, col = qsub * 16 + l15;
            obuf[row][col] = (w == 0) ? v : obuf[row][col] + v;
          }
    }
    __syncthreads();
  }
#pragma unroll
  for (int qsub = 0; qsub < 4; ++qsub) {
    float iv = inv[qsub];
    int col = qsub * 16 + l15;
    bf16x4 pk = {bfs(obuf[wave * 16 + g * 4 + 0][col] * iv),
                 bfs(obuf[wave * 16 + g * 4 + 1][col] * iv),
                 bfs(obuf[wave * 16 + g * 4 + 2][col] * iv),
                 bfs(obuf[wave * 16 + g * 4 + 3][col] * iv)};
    bf16* Op = ao + ((size_t)b * N_N + q0 + col) * 256 +
               h * 64 + wave * 16 + g * 4;
    *reinterpret_cast<bf16x4*>(Op) = pk;
  }
}

// ---------------- proj GEMM (fragment-order A) + bias + residual ------------
__global__ __launch_bounds__(256) void proj_gemm(const bf16* __restrict__ wpb,
                                                 const bf16* __restrict__ ao,
                                                 const float* __restrict__ bproj,
                                                 const float* __restrict__ x,
                                                 float* __restrict__ out) {
  int id = (blockIdx.x & 7) * 72 + (blockIdx.x >> 3);
  int nt = id % 18, ot = (id / 18) & 3, b = id / 72;
  int o0 = ot * 64, n0 = nt * 128;
  int lane = threadIdx.x & 63, wave = threadIdx.x >> 6;
  int l15 = lane & 15, g = lane >> 4, g8 = g * 8;
  const bf16* Af = wpb + (size_t)ot * 16384 + lane * 8;  // fragment-order A
  const bf16* Bb = ao + ((size_t)b * N_N + n0 + wave * 32 + l15) * 256 + g8;
  f32x4 z = {0.f, 0.f, 0.f, 0.f};
  f32x4 acc[4][2];
#pragma unroll
  for (int i = 0; i < 4; ++i) { acc[i][0] = z; acc[i][1] = z; }
#pragma unroll
  for (int kk = 0; kk < 8; ++kk) {
    int co = kk * 32;
    bf16x8 b0 = *(const bf16x8*)(Bb + co);
    bf16x8 b1 = *(const bf16x8*)(Bb + 16 * 256 + co);
#pragma unroll
    for (int mb = 0; mb < 4; ++mb) {
      bf16x8 aa = *(const bf16x8*)(Af + (size_t)(mb * 8 + kk) * 512);
      acc[mb][0] = mfma32(aa, b0, acc[mb][0]);
      acc[mb][1] = mfma32(aa, b1, acc[mb][1]);
    }
  }
  int jb = n0 + wave * 32;
#pragma unroll
  for (int mb = 0; mb < 4; ++mb) {
    int ob = o0 + mb * 16 + g * 4;
    f32x4 bp = *(const f32x4*)(bproj + ob);
#pragma unroll
    for (int nb = 0; nb < 2; ++nb) {
      int n = jb + nb * 16 + l15;
#pragma unroll
      for (int r = 0; r < 4; ++r) {
        size_t idx = ((size_t)b * 256 + ob + r) * N_N + n;
        out[idx] = acc[mb][nb][r] + bp[r] + x[idx];
      }
    }
  }
}

// ---------------- host launch ------------------------------------------------
extern "C" void kernel_launch(void* const* d_in, const int* in_sizes, int n_in,
                              void* d_out, int out_size, void* d_ws, size_t ws_size,
                              hipStream_t stream) {
  (void)in_sizes; (void)n_in; (void)out_size; (void)ws_size;
  const float* x     = (const float*)d_in[0];
  const int*   mask  = (const int*)d_in[1];
  const float* gnw   = (const float*)d_in[2];
  const float* gnb   = (const float*)d_in[3];
  const float* wqkv  = (const float*)d_in[4];
  const float* wproj = (const float*)d_in[5];
  const float* bproj = (const float*)d_in[6];
  float* out = (float*)d_out;
  char* ws = (char*)d_ws;

  float* part  = (float*)(ws + 0);           // 2048 B
  int*   count = (int*)(ws + 2112);          // 32 B
  int*   cidx  = (int*)(ws + 2560);          // 73728 B -> ends 76288
  bf16*  wqb   = (bf16*)(ws + 76288);        // 393216 B -> ends 469504
  bf16*  wpb   = (bf16*)(ws + 469504);       // 131072 B -> ends 600576
  bf16*  xt    = (bf16*)(ws + 600576);       // 9437184 B -> ends 10037760
  bf16*  qkv   = (bf16*)(ws + 10037760);     // 28311552 B -> ends ~38.3 MB
  bf16*  ao    = xt;  // xt dead after qkv_mfma

  prelude<<<1032, 256, 0, stream>>>(x, mask, wqkv, wproj, part, cidx, count,
                                    wqb, wpb);
  xt_gn<<<1152, 256, 0, stream>>>(x, part, gnw, gnb, xt);
  qkv_mfma<<<1728, 256, 0, stream>>>(wqb, xt, cidx, count, qkv);
  attn_reg<<<1152, 256, 0, stream>>>(qkv, count, ao);
  proj_gemm<<<576, 256, 0, stream>>>(wpb, ao, bproj, x, out);
}

// Round 23
// 96.039 us; speedup vs baseline: 1.0280x; 1.0280x over previous
//
#include <hip/hip_runtime.h>
#include <hip/hip_bf16.h>

typedef __hip_bfloat16 bf16;
typedef short bf16x4 __attribute__((ext_vector_type(4)));
typedef short bf16x8 __attribute__((ext_vector_type(8)));
typedef float f32x4 __attribute__((ext_vector_type(4)));

#define N_B 8
#define N_C 256
#define N_H 4
#define N_N 2304
#define N_ELEM 589824   // N_C * N_N

static __device__ __forceinline__ f32x4 mfma32(bf16x8 a, bf16x8 b, f32x4 c) {
  return __builtin_amdgcn_mfma_f32_16x16x32_bf16(a, b, c, 0, 0, 0);
}
static __device__ __forceinline__ short bfs(float f) {
  union { __hip_bfloat16 h; short s; } u;
  u.h = __float2bfloat16(f);
  return u.s;
}
static __device__ __forceinline__ float fexp2(float x) {
#if __has_builtin(__builtin_amdgcn_exp2f)
  return __builtin_amdgcn_exp2f(x);   // raw v_exp_f32; inputs bounded here
#else
  return exp2f(x);
#endif
}
struct TrueT  { static constexpr bool value = true;  };
struct FalseT { static constexpr bool value = false; };

// fragment-order index for weight matrices: element (row, c) ->
// ((ot*4+mb)*8+kk)*512 + (g*16+l15)*8 + e   (lane-contiguous A loads)
static __device__ __forceinline__ size_t wfrag_idx(int row, int c) {
  int ot = row >> 6, rlo = row & 63;
  int mb = rlo >> 4, l15 = rlo & 15;
  int kk = c >> 5, clo = c & 31;
  int gg = clo >> 3, e = clo & 7;
  return ((size_t)((ot * 4 + mb) * 8 + kk)) * 512 + (size_t)(gg * 16 + l15) * 8 + e;
}

// ---------------- fused prelude: gn_stats | mask_scan | w_conv --------------
__global__ __launch_bounds__(256) void prelude(const float* __restrict__ x,
                                               const int* __restrict__ mask,
                                               const float* __restrict__ wq,
                                               const float* __restrict__ wp,
                                               float* __restrict__ part,
                                               int* __restrict__ cidx,
                                               int* __restrict__ count,
                                               bf16* __restrict__ wqb,
                                               bf16* __restrict__ wpb) {
  __shared__ int sbuf[256];
  int bid = blockIdx.x, tid = threadIdx.x;
  if (bid < 256) {
    int b = bid >> 5, chunk = bid & 31;
    const f32x4* p = (const f32x4*)(x + (size_t)b * N_ELEM + (size_t)chunk * 18432);
    float s = 0.f, ss = 0.f;
    for (int i = tid; i < 4608; i += 256) {
      f32x4 v = p[i];
      s  += (v[0] + v[1]) + (v[2] + v[3]);
      ss += (v[0] * v[0] + v[1] * v[1]) + (v[2] * v[2] + v[3] * v[3]);
    }
    for (int off = 32; off; off >>= 1) {
      s  += __shfl_xor(s, off);
      ss += __shfl_xor(ss, off);
    }
    float* ls = (float*)sbuf;
    int wv = tid >> 6;
    if ((tid & 63) == 0) { ls[wv] = s; ls[4 + wv] = ss; }
    __syncthreads();
    if (tid == 0) {
      part[bid * 2]     = ls[0] + ls[1] + ls[2] + ls[3];
      part[bid * 2 + 1] = ls[4] + ls[5] + ls[6] + ls[7];
    }
  } else if (bid < 264) {
    int b = bid - 256;
    const int* mb = mask + b * N_N;
    int flags[9], tot = 0;
    for (int r = 0; r < 9; ++r) {
      int f = (mb[tid * 9 + r] != 0) ? 1 : 0;
      flags[r] = f; tot += f;
    }
    sbuf[tid] = tot;
    __syncthreads();
    for (int off = 1; off < 256; off <<= 1) {
      int v = (tid >= off) ? sbuf[tid - off] : 0;
      __syncthreads();
      sbuf[tid] += v;
      __syncthreads();
    }
    int pos = sbuf[tid] - tot;
    int total = sbuf[255];
    int* cb = cidx + b * N_N;
    for (int r = 0; r < 9; ++r)
      if (flags[r]) cb[pos++] = tid * 9 + r;
    for (int j = total + tid; j < N_N; j += 256) cb[j] = 0;  // finite pad
    if (tid == 0) count[b] = total;
  } else {
    int i = (bid - 264) * 256 + tid;
    int row = i >> 8, c = i & 255;
    float sc = (row < 256) ? 0.18033688011112042f : 1.0f;  // 2^-3 * log2(e)
    wqb[wfrag_idx(row, c)] = __float2bfloat16(wq[i] * sc);
    if (i < 65536) wpb[wfrag_idx(row, c)] = __float2bfloat16(wp[i]);
  }
}

// ---------------- fused stats-final + GN + transpose -------------------------
__global__ __launch_bounds__(256) void xt_gn(const float* __restrict__ x,
                                             const float* __restrict__ part,
                                             const float* __restrict__ gnw,
                                             const float* __restrict__ gnb,
                                             bf16* __restrict__ xt) {
  int id = blockIdx.x;               // 1152 = 36nt * 4ct * 8b
  int nt = id % 36, ct = (id / 36) & 3, b = id / 144;
  float s = 0.f, ss = 0.f;
  for (int i = 0; i < 32; ++i) {
    s  += part[b * 64 + i * 2];
    ss += part[b * 64 + i * 2 + 1];
  }
  float mean = s * (1.f / (float)N_ELEM);
  float var  = ss * (1.f / (float)N_ELEM) - mean * mean;
  float rstd = rsqrtf(var + 1e-5f);
  __shared__ bf16 tile[64][65];
  int tn = threadIdx.x & 63, tq = threadIdx.x >> 6;
  const float* xp = x + (size_t)b * N_ELEM + (size_t)(ct * 64) * N_N + nt * 64;
  for (int it = 0; it < 16; ++it) {
    int c = tq * 16 + it;
    int cg = ct * 64 + c;
    float a  = rstd * gnw[cg];
    float dd = gnb[cg] - mean * a;
    tile[c][tn] = __float2bfloat16(xp[(size_t)c * N_N + tn] * a + dd);
  }
  __syncthreads();
  bf16* xo = xt + ((size_t)b * N_N + nt * 64) * 256 + ct * 64;
  for (int it = 0; it < 16; ++it) {
    int nl = tq * 16 + it;
    xo[(size_t)nl * 256 + tn] = tile[tn][nl];
  }
}

// ---------------- QKV GEMM (MFMA; fragment-order A; fragment-order K/V out) -
__global__ __launch_bounds__(256) void qkv_mfma(const bf16* __restrict__ wqb,
                                                const bf16* __restrict__ xt,
                                                const int* __restrict__ cidx,
                                                const int* __restrict__ count,
                                                bf16* __restrict__ qkv) {
  int id = (blockIdx.x & 7) * 216 + (blockIdx.x >> 3);
  int nt = id % 18, ot = (id / 18) % 12, b = id / 216;
  int o0 = ot * 64, n0 = nt * 128;
  int seg = o0 >> 8, h = (o0 >> 6) & 3;
  if (seg != 0) {                     // skip K/V cols beyond ceil128(cnt)
    int cnt128 = (count[b] + 127) & ~127;
    if (n0 >= cnt128) return;
  }
  int lane = threadIdx.x & 63, wave = threadIdx.x >> 6;
  int l15 = lane & 15, g = lane >> 4, g8 = g * 8;
  int jb = n0 + wave * 32;
  int j0 = jb + l15, j1 = j0 + 16;
  int r0 = j0, r1 = j1;
  if (seg != 0) {
    const int* cb = cidx + b * N_N;
    r0 = cb[j0]; r1 = cb[j1];
  }
  const bf16* Af = wqb + (size_t)ot * 16384 + lane * 8;  // fragment-order A
  const bf16* B0 = xt + ((size_t)b * N_N + r0) * 256 + g8;
  const bf16* B1 = xt + ((size_t)b * N_N + r1) * 256 + g8;
  f32x4 z = {0.f, 0.f, 0.f, 0.f};
  f32x4 acc[4][2];
#pragma unroll
  for (int i = 0; i < 4; ++i) { acc[i][0] = z; acc[i][1] = z; }
#pragma unroll
  for (int kk = 0; kk < 8; ++kk) {
    int co = kk * 32;
    bf16x8 b0 = *(const bf16x8*)(B0 + co);
    bf16x8 b1 = *(const bf16x8*)(B1 + co);
#pragma unroll
    for (int mb = 0; mb < 4; ++mb) {
      bf16x8 aa = *(const bf16x8*)(Af + (size_t)(mb * 8 + kk) * 512);
      acc[mb][0] = mfma32(aa, b0, acc[mb][0]);
      acc[mb][1] = mfma32(aa, b1, acc[mb][1]);
    }
  }
  bf16* Base = qkv + ((size_t)seg * (N_B * N_H) + (size_t)b * N_H + h) *
               ((size_t)N_N * 64);
  if (seg == 0) {
#pragma unroll
    for (int mb = 0; mb < 4; ++mb) {
#pragma unroll
      for (int nb = 0; nb < 2; ++nb) {
        int row = jb + nb * 16 + l15;
        int d0 = mb * 16 + g * 4;
        bf16x4 pk = {bfs(acc[mb][nb][0]), bfs(acc[mb][nb][1]),
                     bfs(acc[mb][nb][2]), bfs(acc[mb][nb][3])};
        *reinterpret_cast<bf16x4*>(Base + (size_t)row * 64 + d0) = pk;
      }
    }
  } else if (seg == 1) {
    // Kf fragment blocks (verified R20)
    int kgb = jb >> 4;
#pragma unroll
    for (int mb = 0; mb < 4; ++mb) {
      int hf = mb >> 1;
      int gp = (mb & 1) * 2 + (g >> 1);
      size_t cellbase = (size_t)(gp * 16 + l15) * 8 + (g & 1) * 4;
#pragma unroll
      for (int nb = 0; nb < 2; ++nb) {
        bf16x4 pk = {bfs(acc[mb][nb][0]), bfs(acc[mb][nb][1]),
                     bfs(acc[mb][nb][2]), bfs(acc[mb][nb][3])};
        size_t off = ((size_t)(kgb + nb) * 2 + hf) * 512 + cellbase;
        *reinterpret_cast<bf16x4*>(Base + off) = pk;
      }
    }
  } else {
    // Vf fragment blocks (verified R20)
#pragma unroll
    for (int mb = 0; mb < 4; ++mb) {
#pragma unroll
      for (int nb = 0; nb < 2; ++nb) {
        int n = jb + nb * 16 + l15;
        int kt = n >> 7, nk = n & 127;
        int half = (nk >> 6) & 1, w = (nk >> 4) & 3;
        int gc = (nk >> 2) & 3, ks = nk & 3;
        size_t blk = ((size_t)(kt * 4 + w) * 4 + mb) * 512;
#pragma unroll
        for (int r = 0; r < 4; ++r) {
          int dlo = g * 4 + r;
          Base[blk + (size_t)(gc * 16 + dlo) * 8 + half * 4 + ks] =
              __float2bfloat16(acc[mb][nb][r]);
        }
      }
    }
  }
}

// ---------------- fixed-reference-softmax flash attention (R21 best) --------
// 4 waves split by key-group, full 64q x 64d per wave, Q in VGPR, pure-sum
// softmax, fragment-order K/V (lane-contiguous 16B loads), raw v_exp_f32.
// No prefetch (R13/R15/R19 spilled; R22's reg double-buffer cost VALU).
__global__ __launch_bounds__(256, 2) void attn_reg(const bf16* __restrict__ qkv,
                                                   const int* __restrict__ count,
                                                   bf16* __restrict__ ao) {
  int id = (blockIdx.x & 7) * 144 + (blockIdx.x >> 3);
  int qt = id % 36, h = (id / 36) & 3, b = id / 144;
  int tid = threadIdx.x;
  int lane = tid & 63, wave = tid >> 6;
  int l15 = lane & 15, g = lane >> 4, g8 = g * 8;
  int q0 = qt * 64;
  const size_t HSZ = (size_t)N_N * 64;
  const bf16* Qb = qkv + ((size_t)b * N_H + h) * HSZ;
  const bf16* Kf = qkv + ((size_t)(N_B * N_H) + (size_t)b * N_H + h) * HSZ;
  const bf16* Vf = qkv + ((size_t)(2 * N_B * N_H) + (size_t)b * N_H + h) * HSZ;
  int cnt = count[b];

  __shared__ float ssh[4][64];
  __shared__ float obuf[64][65];

  bf16x8 qf[4][2];
#pragma unroll
  for (int qsub = 0; qsub < 4; ++qsub) {
    const bf16* Qp = Qb + (size_t)(q0 + qsub * 16 + l15) * 64;
    qf[qsub][0] = *(const bf16x8*)(Qp + g8);
    qf[qsub][1] = *(const bf16x8*)(Qp + 32 + g8);
  }
  f32x4 z = {0.f, 0.f, 0.f, 0.f};
  f32x4 acc[4][4];   // [dblock][qsub]: O[d=dblock*16+g*4+r][q=qsub*16+l15]
#pragma unroll
  for (int i = 0; i < 4; ++i)
#pragma unroll
    for (int j = 0; j < 4; ++j) acc[i][j] = z;
  float s_r[4] = {0.f, 0.f, 0.f, 0.f};   // lane-local partial denominators
  int kw = wave * 16;
  int lane8 = lane * 8;
  const float NEG = -3.0e38f;

  auto step = [&](int kb, auto tail_t) {
    constexpr bool TAIL = decltype(tail_t)::value;
    int kg0 = (kb >> 4) + wave;
    int kg1 = kg0 + 4;
    bf16x8 k0lo = *(const bf16x8*)(Kf + (size_t)(kg0 * 2 + 0) * 512 + lane8);
    bf16x8 k0hi = *(const bf16x8*)(Kf + (size_t)(kg0 * 2 + 1) * 512 + lane8);
    bf16x8 k1lo = *(const bf16x8*)(Kf + (size_t)(kg1 * 2 + 0) * 512 + lane8);
    bf16x8 k1hi = *(const bf16x8*)(Kf + (size_t)(kg1 * 2 + 1) * 512 + lane8);
    int base0 = kb + kw + g * 4, base1 = base0 + 64;

    bf16x8 pb[4];
#pragma unroll
    for (int qsub = 0; qsub < 4; ++qsub) {
      f32x4 s0 = z, s1 = z;
      s0 = mfma32(k0lo, qf[qsub][0], s0);
      s0 = mfma32(k0hi, qf[qsub][1], s0);
      s1 = mfma32(k1lo, qf[qsub][0], s1);
      s1 = mfma32(k1hi, qf[qsub][1], s1);
      float a0, a1, a2, a3, a4, a5, a6, a7;
      if constexpr (TAIL) {
        a0 = (base0 + 0 < cnt) ? s0[0] : NEG;
        a1 = (base0 + 1 < cnt) ? s0[1] : NEG;
        a2 = (base0 + 2 < cnt) ? s0[2] : NEG;
        a3 = (base0 + 3 < cnt) ? s0[3] : NEG;
        a4 = (base1 + 0 < cnt) ? s1[0] : NEG;
        a5 = (base1 + 1 < cnt) ? s1[1] : NEG;
        a6 = (base1 + 2 < cnt) ? s1[2] : NEG;
        a7 = (base1 + 3 < cnt) ? s1[3] : NEG;
      } else {
        a0 = s0[0]; a1 = s0[1]; a2 = s0[2]; a3 = s0[3];
        a4 = s1[0]; a5 = s1[1]; a6 = s1[2]; a7 = s1[3];
      }
      float p0 = fexp2(a0), p1 = fexp2(a1);
      float p2 = fexp2(a2), p3 = fexp2(a3);
      float p4 = fexp2(a4), p5 = fexp2(a5);
      float p6 = fexp2(a6), p7 = fexp2(a7);
      s_r[qsub] += ((p0 + p1) + (p2 + p3)) + ((p4 + p5) + (p6 + p7));
      pb[qsub] = bf16x8{bfs(p0), bfs(p1), bfs(p2), bfs(p3),
                        bfs(p4), bfs(p5), bfs(p6), bfs(p7)};
    }
    int kt = kb >> 7;
    size_t vbase = (size_t)(kt * 4 + wave) * 4 * 512 + lane8;
#pragma unroll
    for (int dblock = 0; dblock < 4; ++dblock) {
      bf16x8 vf = *(const bf16x8*)(Vf + vbase + (size_t)dblock * 512);
#pragma unroll
      for (int qsub = 0; qsub < 4; ++qsub)
        acc[dblock][qsub] = mfma32(vf, pb[qsub], acc[dblock][qsub]);
    }
  };

  int kb = 0;
  for (; kb + 128 <= cnt; kb += 128) step(kb, FalseT{});
  if (kb < cnt) step(kb, TrueT{});

  // ---- denominator: cross-lane (once), then cross-wave via LDS ----
#pragma unroll
  for (int qsub = 0; qsub < 4; ++qsub) {
    float s = s_r[qsub];
    s += __shfl_xor(s, 16);
    s += __shfl_xor(s, 32);
    s_r[qsub] = s;
  }
  if (g == 0) {
#pragma unroll
    for (int qsub = 0; qsub < 4; ++qsub)
      ssh[wave][qsub * 16 + l15] = s_r[qsub];
  }
  __syncthreads();
  float inv[4];
#pragma unroll
  for (int qsub = 0; qsub < 4; ++qsub) {
    int q = qsub * 16 + l15;
    float St = (ssh[0][q] + ssh[1][q]) + (ssh[2][q] + ssh[3][q]);
    inv[qsub] = (St > 0.f) ? (1.f / St) : 0.f;
  }
  // ---- cross-wave O accumulation (pure sums, no rescale) ----
#pragma unroll
  for (int w = 0; w < 4; ++w) {
    if (wave == w) {
#pragma unroll
      for (int dblock = 0; dblock < 4; ++dblock)
#pragma unroll
        for (int qsub = 0; qsub < 4; ++qsub)
#pragma unroll
          for (int r = 0; r < 4; ++r) {
            float v = acc[dblock][qsub][r];
            int row = dblock * 16 + g * 4 + r, col = qsub * 16 + l15;
            obuf[row][col] = (w == 0) ? v : obuf[row][col] + v;
          }
    }
    __syncthreads();
  }
#pragma unroll
  for (int qsub = 0; qsub < 4; ++qsub) {
    float iv = inv[qsub];
    int col = qsub * 16 + l15;
    bf16x4 pk = {bfs(obuf[wave * 16 + g * 4 + 0][col] * iv),
                 bfs(obuf[wave * 16 + g * 4 + 1][col] * iv),
                 bfs(obuf[wave * 16 + g * 4 + 2][col] * iv),
                 bfs(obuf[wave * 16 + g * 4 + 3][col] * iv)};
    bf16* Op = ao + ((size_t)b * N_N + q0 + col) * 256 +
               h * 64 + wave * 16 + g * 4;
    *reinterpret_cast<bf16x4*>(Op) = pk;
  }
}

// ---------------- proj GEMM (fragment-order A) + bias + residual ------------
__global__ __launch_bounds__(256) void proj_gemm(const bf16* __restrict__ wpb,
                                                 const bf16* __restrict__ ao,
                                                 const float* __restrict__ bproj,
                                                 const float* __restrict__ x,
                                                 float* __restrict__ out) {
  int id = (blockIdx.x & 7) * 72 + (blockIdx.x >> 3);
  int nt = id % 18, ot = (id / 18) & 3, b = id / 72;
  int o0 = ot * 64, n0 = nt * 128;
  int lane = threadIdx.x & 63, wave = threadIdx.x >> 6;
  int l15 = lane & 15, g = lane >> 4, g8 = g * 8;
  const bf16* Af = wpb + (size_t)ot * 16384 + lane * 8;  // fragment-order A
  const bf16* Bb = ao + ((size_t)b * N_N + n0 + wave * 32 + l15) * 256 + g8;
  f32x4 z = {0.f, 0.f, 0.f, 0.f};
  f32x4 acc[4][2];
#pragma unroll
  for (int i = 0; i < 4; ++i) { acc[i][0] = z; acc[i][1] = z; }
#pragma unroll
  for (int kk = 0; kk < 8; ++kk) {
    int co = kk * 32;
    bf16x8 b0 = *(const bf16x8*)(Bb + co);
    bf16x8 b1 = *(const bf16x8*)(Bb + 16 * 256 + co);
#pragma unroll
    for (int mb = 0; mb < 4; ++mb) {
      bf16x8 aa = *(const bf16x8*)(Af + (size_t)(mb * 8 + kk) * 512);
      acc[mb][0] = mfma32(aa, b0, acc[mb][0]);
      acc[mb][1] = mfma32(aa, b1, acc[mb][1]);
    }
  }
  int jb = n0 + wave * 32;
#pragma unroll
  for (int mb = 0; mb < 4; ++mb) {
    int ob = o0 + mb * 16 + g * 4;
    f32x4 bp = *(const f32x4*)(bproj + ob);
#pragma unroll
    for (int nb = 0; nb < 2; ++nb) {
      int n = jb + nb * 16 + l15;
#pragma unroll
      for (int r = 0; r < 4; ++r) {
        size_t idx = ((size_t)b * 256 + ob + r) * N_N + n;
        out[idx] = acc[mb][nb][r] + bp[r] + x[idx];
      }
    }
  }
}

// ---------------- host launch ------------------------------------------------
extern "C" void kernel_launch(void* const* d_in, const int* in_sizes, int n_in,
                              void* d_out, int out_size, void* d_ws, size_t ws_size,
                              hipStream_t stream) {
  (void)in_sizes; (void)n_in; (void)out_size; (void)ws_size;
  const float* x     = (const float*)d_in[0];
  const int*   mask  = (const int*)d_in[1];
  const float* gnw   = (const float*)d_in[2];
  const float* gnb   = (const float*)d_in[3];
  const float* wqkv  = (const float*)d_in[4];
  const float* wproj = (const float*)d_in[5];
  const float* bproj = (const float*)d_in[6];
  float* out = (float*)d_out;
  char* ws = (char*)d_ws;

  float* part  = (float*)(ws + 0);           // 2048 B
  int*   count = (int*)(ws + 2112);          // 32 B
  int*   cidx  = (int*)(ws + 2560);          // 73728 B -> ends 76288
  bf16*  wqb   = (bf16*)(ws + 76288);        // 393216 B -> ends 469504
  bf16*  wpb   = (bf16*)(ws + 469504);       // 131072 B -> ends 600576
  bf16*  xt    = (bf16*)(ws + 600576);       // 9437184 B -> ends 10037760
  bf16*  qkv   = (bf16*)(ws + 10037760);     // 28311552 B -> ends ~38.3 MB
  bf16*  ao    = xt;  // xt dead after qkv_mfma

  prelude<<<1032, 256, 0, stream>>>(x, mask, wqkv, wproj, part, cidx, count,
                                    wqb, wpb);
  xt_gn<<<1152, 256, 0, stream>>>(x, part, gnw, gnb, xt);
  qkv_mfma<<<1728, 256, 0, stream>>>(wqb, xt, cidx, count, qkv);
  attn_reg<<<1152, 256, 0, stream>>>(qkv, count, ao);
  proj_gemm<<<576, 256, 0, stream>>>(wpb, ao, bproj, x, out);
}

// Round 24
// 95.741 us; speedup vs baseline: 1.0312x; 1.0031x over previous
//
#include <hip/hip_runtime.h>
#include <hip/hip_bf16.h>

typedef __hip_bfloat16 bf16;
typedef short bf16x4 __attribute__((ext_vector_type(4)));
typedef short bf16x8 __attribute__((ext_vector_type(8)));
typedef float f32x4 __attribute__((ext_vector_type(4)));

#define N_B 8
#define N_C 256
#define N_H 4
#define N_N 2304
#define N_ELEM 589824   // N_C * N_N

static __device__ __forceinline__ f32x4 mfma32(bf16x8 a, bf16x8 b, f32x4 c) {
  return __builtin_amdgcn_mfma_f32_16x16x32_bf16(a, b, c, 0, 0, 0);
}
static __device__ __forceinline__ short bfs(float f) {
  union { __hip_bfloat16 h; short s; } u;
  u.h = __float2bfloat16(f);
  return u.s;
}
static __device__ __forceinline__ float fexp2(float x) {
#if __has_builtin(__builtin_amdgcn_exp2f)
  return __builtin_amdgcn_exp2f(x);   // raw v_exp_f32; inputs bounded here
#else
  return exp2f(x);
#endif
}
struct TrueT  { static constexpr bool value = true;  };
struct FalseT { static constexpr bool value = false; };

// fragment-order index for weight matrices: element (row, c) ->
// ((ot*4+mb)*8+kk)*512 + (g*16+l15)*8 + e   (lane-contiguous A loads)
static __device__ __forceinline__ size_t wfrag_idx(int row, int c) {
  int ot = row >> 6, rlo = row & 63;
  int mb = rlo >> 4, l15 = rlo & 15;
  int kk = c >> 5, clo = c & 31;
  int gg = clo >> 3, e = clo & 7;
  return ((size_t)((ot * 4 + mb) * 8 + kk)) * 512 + (size_t)(gg * 16 + l15) * 8 + e;
}

// ---------------- fused prelude: gn_stats | mask_scan | w_conv --------------
__global__ __launch_bounds__(256) void prelude(const float* __restrict__ x,
                                               const int* __restrict__ mask,
                                               const float* __restrict__ wq,
                                               const float* __restrict__ wp,
                                               float* __restrict__ part,
                                               int* __restrict__ cidx,
                                               int* __restrict__ count,
                                               bf16* __restrict__ wqb,
                                               bf16* __restrict__ wpb) {
  __shared__ int sbuf[256];
  int bid = blockIdx.x, tid = threadIdx.x;
  if (bid < 256) {
    int b = bid >> 5, chunk = bid & 31;
    const f32x4* p = (const f32x4*)(x + (size_t)b * N_ELEM + (size_t)chunk * 18432);
    float s = 0.f, ss = 0.f;
    for (int i = tid; i < 4608; i += 256) {
      f32x4 v = p[i];
      s  += (v[0] + v[1]) + (v[2] + v[3]);
      ss += (v[0] * v[0] + v[1] * v[1]) + (v[2] * v[2] + v[3] * v[3]);
    }
    for (int off = 32; off; off >>= 1) {
      s  += __shfl_xor(s, off);
      ss += __shfl_xor(ss, off);
    }
    float* ls = (float*)sbuf;
    int wv = tid >> 6;
    if ((tid & 63) == 0) { ls[wv] = s; ls[4 + wv] = ss; }
    __syncthreads();
    if (tid == 0) {
      part[bid * 2]     = ls[0] + ls[1] + ls[2] + ls[3];
      part[bid * 2 + 1] = ls[4] + ls[5] + ls[6] + ls[7];
    }
  } else if (bid < 264) {
    int b = bid - 256;
    const int* mb = mask + b * N_N;
    int flags[9], tot = 0;
    for (int r = 0; r < 9; ++r) {
      int f = (mb[tid * 9 + r] != 0) ? 1 : 0;
      flags[r] = f; tot += f;
    }
    sbuf[tid] = tot;
    __syncthreads();
    for (int off = 1; off < 256; off <<= 1) {
      int v = (tid >= off) ? sbuf[tid - off] : 0;
      __syncthreads();
      sbuf[tid] += v;
      __syncthreads();
    }
    int pos = sbuf[tid] - tot;
    int total = sbuf[255];
    int* cb = cidx + b * N_N;
    for (int r = 0; r < 9; ++r)
      if (flags[r]) cb[pos++] = tid * 9 + r;
    for (int j = total + tid; j < N_N; j += 256) cb[j] = 0;  // finite pad
    if (tid == 0) count[b] = total;
  } else {
    int i = (bid - 264) * 256 + tid;
    int row = i >> 8, c = i & 255;
    float sc = (row < 256) ? 0.18033688011112042f : 1.0f;  // 2^-3 * log2(e)
    wqb[wfrag_idx(row, c)] = __float2bfloat16(wq[i] * sc);
    if (i < 65536) wpb[wfrag_idx(row, c)] = __float2bfloat16(wp[i]);
  }
}

// ---------------- fused stats-final + GN + transpose -------------------------
__global__ __launch_bounds__(256) void xt_gn(const float* __restrict__ x,
                                             const float* __restrict__ part,
                                             const float* __restrict__ gnw,
                                             const float* __restrict__ gnb,
                                             bf16* __restrict__ xt) {
  int id = blockIdx.x;               // 1152 = 36nt * 4ct * 8b
  int nt = id % 36, ct = (id / 36) & 3, b = id / 144;
  float s = 0.f, ss = 0.f;
  for (int i = 0; i < 32; ++i) {
    s  += part[b * 64 + i * 2];
    ss += part[b * 64 + i * 2 + 1];
  }
  float mean = s * (1.f / (float)N_ELEM);
  float var  = ss * (1.f / (float)N_ELEM) - mean * mean;
  float rstd = rsqrtf(var + 1e-5f);
  __shared__ bf16 tile[64][65];
  int tn = threadIdx.x & 63, tq = threadIdx.x >> 6;
  const float* xp = x + (size_t)b * N_ELEM + (size_t)(ct * 64) * N_N + nt * 64;
  for (int it = 0; it < 16; ++it) {
    int c = tq * 16 + it;
    int cg = ct * 64 + c;
    float a  = rstd * gnw[cg];
    float dd = gnb[cg] - mean * a;
    tile[c][tn] = __float2bfloat16(xp[(size_t)c * N_N + tn] * a + dd);
  }
  __syncthreads();
  bf16* xo = xt + ((size_t)b * N_N + nt * 64) * 256 + ct * 64;
  for (int it = 0; it < 16; ++it) {
    int nl = tq * 16 + it;
    xo[(size_t)nl * 256 + tn] = tile[tn][nl];
  }
}

// ---------------- QKV GEMM (MFMA; fragment-order A; fragment-order K/V out) -
__global__ __launch_bounds__(256) void qkv_mfma(const bf16* __restrict__ wqb,
                                                const bf16* __restrict__ xt,
                                                const int* __restrict__ cidx,
                                                const int* __restrict__ count,
                                                bf16* __restrict__ qkv) {
  int id = (blockIdx.x & 7) * 216 + (blockIdx.x >> 3);
  int nt = id % 18, ot = (id / 18) % 12, b = id / 216;
  int o0 = ot * 64, n0 = nt * 128;
  int seg = o0 >> 8, h = (o0 >> 6) & 3;
  if (seg != 0) {                     // skip K/V cols beyond ceil128(cnt)
    int cnt128 = (count[b] + 127) & ~127;
    if (n0 >= cnt128) return;
  }
  int lane = threadIdx.x & 63, wave = threadIdx.x >> 6;
  int l15 = lane & 15, g = lane >> 4, g8 = g * 8;
  int jb = n0 + wave * 32;
  int j0 = jb + l15, j1 = j0 + 16;
  int r0 = j0, r1 = j1;
  if (seg != 0) {
    const int* cb = cidx + b * N_N;
    r0 = cb[j0]; r1 = cb[j1];
  }
  const bf16* Af = wqb + (size_t)ot * 16384 + lane * 8;  // fragment-order A
  const bf16* B0 = xt + ((size_t)b * N_N + r0) * 256 + g8;
  const bf16* B1 = xt + ((size_t)b * N_N + r1) * 256 + g8;
  f32x4 z = {0.f, 0.f, 0.f, 0.f};
  f32x4 acc[4][2];
#pragma unroll
  for (int i = 0; i < 4; ++i) { acc[i][0] = z; acc[i][1] = z; }
#pragma unroll
  for (int kk = 0; kk < 8; ++kk) {
    int co = kk * 32;
    bf16x8 b0 = *(const bf16x8*)(B0 + co);
    bf16x8 b1 = *(const bf16x8*)(B1 + co);
#pragma unroll
    for (int mb = 0; mb < 4; ++mb) {
      bf16x8 aa = *(const bf16x8*)(Af + (size_t)(mb * 8 + kk) * 512);
      acc[mb][0] = mfma32(aa, b0, acc[mb][0]);
      acc[mb][1] = mfma32(aa, b1, acc[mb][1]);
    }
  }
  bf16* Base = qkv + ((size_t)seg * (N_B * N_H) + (size_t)b * N_H + h) *
               ((size_t)N_N * 64);
  if (seg == 0) {
#pragma unroll
    for (int mb = 0; mb < 4; ++mb) {
#pragma unroll
      for (int nb = 0; nb < 2; ++nb) {
        int row = jb + nb * 16 + l15;
        int d0 = mb * 16 + g * 4;
        bf16x4 pk = {bfs(acc[mb][nb][0]), bfs(acc[mb][nb][1]),
                     bfs(acc[mb][nb][2]), bfs(acc[mb][nb][3])};
        *reinterpret_cast<bf16x4*>(Base + (size_t)row * 64 + d0) = pk;
      }
    }
  } else if (seg == 1) {
    // Kf fragment blocks (verified R20)
    int kgb = jb >> 4;
#pragma unroll
    for (int mb = 0; mb < 4; ++mb) {
      int hf = mb >> 1;
      int gp = (mb & 1) * 2 + (g >> 1);
      size_t cellbase = (size_t)(gp * 16 + l15) * 8 + (g & 1) * 4;
#pragma unroll
      for (int nb = 0; nb < 2; ++nb) {
        bf16x4 pk = {bfs(acc[mb][nb][0]), bfs(acc[mb][nb][1]),
                     bfs(acc[mb][nb][2]), bfs(acc[mb][nb][3])};
        size_t off = ((size_t)(kgb + nb) * 2 + hf) * 512 + cellbase;
        *reinterpret_cast<bf16x4*>(Base + off) = pk;
      }
    }
  } else {
    // Vf fragment blocks (verified R20)
#pragma unroll
    for (int mb = 0; mb < 4; ++mb) {
#pragma unroll
      for (int nb = 0; nb < 2; ++nb) {
        int n = jb + nb * 16 + l15;
        int kt = n >> 7, nk = n & 127;
        int half = (nk >> 6) & 1, w = (nk >> 4) & 3;
        int gc = (nk >> 2) & 3, ks = nk & 3;
        size_t blk = ((size_t)(kt * 4 + w) * 4 + mb) * 512;
#pragma unroll
        for (int r = 0; r < 4; ++r) {
          int dlo = g * 4 + r;
          Base[blk + (size_t)(gc * 16 + dlo) * 8 + half * 4 + ks] =
              __float2bfloat16(acc[mb][nb][r]);
        }
      }
    }
  }
}

// ---------------- fixed-reference-softmax flash attention (R21 best) --------
// 4 waves split by key-group, full 64q x 64d per wave, Q in VGPR, pure-sum
// softmax, fragment-order K/V (lane-contiguous 16B loads), raw v_exp_f32.
// No prefetch (R13/R15/R19 spilled; R22's reg double-buffer cost VALU).
__global__ __launch_bounds__(256, 2) void attn_reg(const bf16* __restrict__ qkv,
                                                   const int* __restrict__ count,
                                                   bf16* __restrict__ ao) {
  int id = (blockIdx.x & 7) * 144 + (blockIdx.x >> 3);
  int qt = id % 36, h = (id / 36) & 3, b = id / 144;
  int tid = threadIdx.x;
  int lane = tid & 63, wave = tid >> 6;
  int l15 = lane & 15, g = lane >> 4, g8 = g * 8;
  int q0 = qt * 64;
  const size_t HSZ = (size_t)N_N * 64;
  const bf16* Qb = qkv + ((size_t)b * N_H + h) * HSZ;
  const bf16* Kf = qkv + ((size_t)(N_B * N_H) + (size_t)b * N_H + h) * HSZ;
  const bf16* Vf = qkv + ((size_t)(2 * N_B * N_H) + (size_t)b * N_H + h) * HSZ;
  int cnt = count[b];

  __shared__ float ssh[4][64];
  __shared__ float obuf[64][65];

  bf16x8 qf[4][2];
#pragma unroll
  for (int qsub = 0; qsub < 4; ++qsub) {
    const bf16* Qp = Qb + (size_t)(q0 + qsub * 16 + l15) * 64;
    qf[qsub][0] = *(const bf16x8*)(Qp + g8);
    qf[qsub][1] = *(const bf16x8*)(Qp + 32 + g8);
  }
  f32x4 z = {0.f, 0.f, 0.f, 0.f};
  f32x4 acc[4][4];   // [dblock][qsub]: O[d=dblock*16+g*4+r][q=qsub*16+l15]
#pragma unroll
  for (int i = 0; i < 4; ++i)
#pragma unroll
    for (int j = 0; j < 4; ++j) acc[i][j] = z;
  float s_r[4] = {0.f, 0.f, 0.f, 0.f};   // lane-local partial denominators
  int kw = wave * 16;
  int lane8 = lane * 8;
  const float NEG = -3.0e38f;

  auto step = [&](int kb, auto tail_t) {
    constexpr bool TAIL = decltype(tail_t)::value;
    int kg0 = (kb >> 4) + wave;
    int kg1 = kg0 + 4;
    bf16x8 k0lo = *(const bf16x8*)(Kf + (size_t)(kg0 * 2 + 0) * 512 + lane8);
    bf16x8 k0hi = *(const bf16x8*)(Kf + (size_t)(kg0 * 2 + 1) * 512 + lane8);
    bf16x8 k1lo = *(const bf16x8*)(Kf + (size_t)(kg1 * 2 + 0) * 512 + lane8);
    bf16x8 k1hi = *(const bf16x8*)(Kf + (size_t)(kg1 * 2 + 1) * 512 + lane8);
    int base0 = kb + kw + g * 4, base1 = base0 + 64;

    bf16x8 pb[4];
#pragma unroll
    for (int qsub = 0; qsub < 4; ++qsub) {
      f32x4 s0 = z, s1 = z;
      s0 = mfma32(k0lo, qf[qsub][0], s0);
      s0 = mfma32(k0hi, qf[qsub][1], s0);
      s1 = mfma32(k1lo, qf[qsub][0], s1);
      s1 = mfma32(k1hi, qf[qsub][1], s1);
      float a0, a1, a2, a3, a4, a5, a6, a7;
      if constexpr (TAIL) {
        a0 = (base0 + 0 < cnt) ? s0[0] : NEG;
        a1 = (base0 + 1 < cnt) ? s0[1] : NEG;
        a2 = (base0 + 2 < cnt) ? s0[2] : NEG;
        a3 = (base0 + 3 < cnt) ? s0[3] : NEG;
        a4 = (base1 + 0 < cnt) ? s1[0] : NEG;
        a5 = (base1 + 1 < cnt) ? s1[1] : NEG;
        a6 = (base1 + 2 < cnt) ? s1[2] : NEG;
        a7 = (base1 + 3 < cnt) ? s1[3] : NEG;
      } else {
        a0 = s0[0]; a1 = s0[1]; a2 = s0[2]; a3 = s0[3];
        a4 = s1[0]; a5 = s1[1]; a6 = s1[2]; a7 = s1[3];
      }
      float p0 = fexp2(a0), p1 = fexp2(a1);
      float p2 = fexp2(a2), p3 = fexp2(a3);
      float p4 = fexp2(a4), p5 = fexp2(a5);
      float p6 = fexp2(a6), p7 = fexp2(a7);
      s_r[qsub] += ((p0 + p1) + (p2 + p3)) + ((p4 + p5) + (p6 + p7));
      pb[qsub] = bf16x8{bfs(p0), bfs(p1), bfs(p2), bfs(p3),
                        bfs(p4), bfs(p5), bfs(p6), bfs(p7)};
    }
    int kt = kb >> 7;
    size_t vbase = (size_t)(kt * 4 + wave) * 4 * 512 + lane8;
#pragma unroll
    for (int dblock = 0; dblock < 4; ++dblock) {
      bf16x8 vf = *(const bf16x8*)(Vf + vbase + (size_t)dblock * 512);
#pragma unroll
      for (int qsub = 0; qsub < 4; ++qsub)
        acc[dblock][qsub] = mfma32(vf, pb[qsub], acc[dblock][qsub]);
    }
  };

  int kb = 0;
  for (; kb + 128 <= cnt; kb += 128) step(kb, FalseT{});
  if (kb < cnt) step(kb, TrueT{});

  // ---- denominator: cross-lane (once), then cross-wave via LDS ----
#pragma unroll
  for (int qsub = 0; qsub < 4; ++qsub) {
    float s = s_r[qsub];
    s += __shfl_xor(s, 16);
    s += __shfl_xor(s, 32);
    s_r[qsub] = s;
  }
  if (g == 0) {
#pragma unroll
    for (int qsub = 0; qsub < 4; ++qsub)
      ssh[wave][qsub * 16 + l15] = s_r[qsub];
  }
  __syncthreads();
  float inv[4];
#pragma unroll
  for (int qsub = 0; qsub < 4; ++qsub) {
    int q = qsub * 16 + l15;
    float St = (ssh[0][q] + ssh[1][q]) + (ssh[2][q] + ssh[3][q]);
    inv[qsub] = (St > 0.f) ? (1.f / St) : 0.f;
  }
  // ---- cross-wave O accumulation (pure sums, no rescale) ----
#pragma unroll
  for (int w = 0; w < 4; ++w) {
    if (wave == w) {
#pragma unroll
      for (int dblock = 0; dblock < 4; ++dblock)
#pragma unroll
        for (int qsub = 0; qsub < 4; ++qsub)
#pragma unroll
          for (int r = 0; r < 4; ++r) {
            float v = acc[dblock][qsub][r];
            int row = dblock * 16 + g * 4 + r, col = qsub * 16 + l15;
            obuf[row][col] = (w == 0) ? v : obuf[row][col] + v;
          }
    }
    __syncthreads();
  }
#pragma unroll
  for (int qsub = 0; qsub < 4; ++qsub) {
    float iv = inv[qsub];
    int col = qsub * 16 + l15;
    bf16x4 pk = {bfs(obuf[wave * 16 + g * 4 + 0][col] * iv),
                 bfs(obuf[wave * 16 + g * 4 + 1][col] * iv),
                 bfs(obuf[wave * 16 + g * 4 + 2][col] * iv),
                 bfs(obuf[wave * 16 + g * 4 + 3][col] * iv)};
    bf16* Op = ao + ((size_t)b * N_N + q0 + col) * 256 +
               h * 64 + wave * 16 + g * 4;
    *reinterpret_cast<bf16x4*>(Op) = pk;
  }
}

// ---------------- proj GEMM (fragment-order A) + bias + residual ------------
__global__ __launch_bounds__(256) void proj_gemm(const bf16* __restrict__ wpb,
                                                 const bf16* __restrict__ ao,
                                                 const float* __restrict__ bproj,
                                                 const float* __restrict__ x,
                                                 float* __restrict__ out) {
  int id = (blockIdx.x & 7) * 72 + (blockIdx.x >> 3);
  int nt = id % 18, ot = (id / 18) & 3, b = id / 72;
  int o0 = ot * 64, n0 = nt * 128;
  int lane = threadIdx.x & 63, wave = threadIdx.x >> 6;
  int l15 = lane & 15, g = lane >> 4, g8 = g * 8;
  const bf16* Af = wpb + (size_t)ot * 16384 + lane * 8;  // fragment-order A
  const bf16* Bb = ao + ((size_t)b * N_N + n0 + wave * 32 + l15) * 256 + g8;
  f32x4 z = {0.f, 0.f, 0.f, 0.f};
  f32x4 acc[4][2];
#pragma unroll
  for (int i = 0; i < 4; ++i) { acc[i][0] = z; acc[i][1] = z; }
#pragma unroll
  for (int kk = 0; kk < 8; ++kk) {
    int co = kk * 32;
    bf16x8 b0 = *(const bf16x8*)(Bb + co);
    bf16x8 b1 = *(const bf16x8*)(Bb + 16 * 256 + co);
#pragma unroll
    for (int mb = 0; mb < 4; ++mb) {
      bf16x8 aa = *(const bf16x8*)(Af + (size_t)(mb * 8 + kk) * 512);
      acc[mb][0] = mfma32(aa, b0, acc[mb][0]);
      acc[mb][1] = mfma32(aa, b1, acc[mb][1]);
    }
  }
  int jb = n0 + wave * 32;
#pragma unroll
  for (int mb = 0; mb < 4; ++mb) {
    int ob = o0 + mb * 16 + g * 4;
    f32x4 bp = *(const f32x4*)(bproj + ob);
#pragma unroll
    for (int nb = 0; nb < 2; ++nb) {
      int n = jb + nb * 16 + l15;
#pragma unroll
      for (int r = 0; r < 4; ++r) {
        size_t idx = ((size_t)b * 256 + ob + r) * N_N + n;
        out[idx] = acc[mb][nb][r] + bp[r] + x[idx];
      }
    }
  }
}

// ---------------- host launch ------------------------------------------------
extern "C" void kernel_launch(void* const* d_in, const int* in_sizes, int n_in,
                              void* d_out, int out_size, void* d_ws, size_t ws_size,
                              hipStream_t stream) {
  (void)in_sizes; (void)n_in; (void)out_size; (void)ws_size;
  const float* x     = (const float*)d_in[0];
  const int*   mask  = (const int*)d_in[1];
  const float* gnw   = (const float*)d_in[2];
  const float* gnb   = (const float*)d_in[3];
  const float* wqkv  = (const float*)d_in[4];
  const float* wproj = (const float*)d_in[5];
  const float* bproj = (const float*)d_in[6];
  float* out = (float*)d_out;
  char* ws = (char*)d_ws;

  float* part  = (float*)(ws + 0);           // 2048 B
  int*   count = (int*)(ws + 2112);          // 32 B
  int*   cidx  = (int*)(ws + 2560);          // 73728 B -> ends 76288
  bf16*  wqb   = (bf16*)(ws + 76288);        // 393216 B -> ends 469504
  bf16*  wpb   = (bf16*)(ws + 469504);       // 131072 B -> ends 600576
  bf16*  xt    = (bf16*)(ws + 600576);       // 9437184 B -> ends 10037760
  bf16*  qkv   = (bf16*)(ws + 10037760);     // 28311552 B -> ends ~38.3 MB
  bf16*  ao    = xt;  // xt dead after qkv_mfma

  prelude<<<1032, 256, 0, stream>>>(x, mask, wqkv, wproj, part, cidx, count,
                                    wqb, wpb);
  xt_gn<<<1152, 256, 0, stream>>>(x, part, gnw, gnb, xt);
  qkv_mfma<<<1728, 256, 0, stream>>>(wqb, xt, cidx, count, qkv);
  attn_reg<<<1152, 256, 0, stream>>>(qkv, count, ao);
  proj_gemm<<<576, 256, 0, stream>>>(wpb, ao, bproj, x, out);
}